// Round 1
// baseline (657.303 us; speedup 1.0000x reference)
//
#include <hip/hip_runtime.h>
#include <hip/hip_bf16.h>
#include <stdint.h>

#define B_ 8
#define L_ 2048
#define D_ 1024
#define N_ 16
#define M_ (B_ * L_)   // 16384 rows
#define K_ D_          // 1024

typedef __bf16 bf16;
typedef __bf16 bf16x8 __attribute__((ext_vector_type(8)));
typedef float f32x4 __attribute__((ext_vector_type(4)));

// ---------------- f32 -> bf16 conversion (vectorized x4) ----------------
__global__ __launch_bounds__(256) void cvt_f32_bf16(const float* __restrict__ in,
                                                    bf16* __restrict__ out, int n4) {
  int i = blockIdx.x * 256 + threadIdx.x;
  const int stride = gridDim.x * 256;
  const float4* in4 = (const float4*)in;
  uint2* out2 = (uint2*)out;
  for (; i < n4; i += stride) {
    float4 v = in4[i];
    union { bf16 h[4]; uint2 u; } p;
    p.h[0] = (bf16)v.x; p.h[1] = (bf16)v.y; p.h[2] = (bf16)v.z; p.h[3] = (bf16)v.w;
    out2[i] = p.u;
  }
}

// ---------------- async global->LDS helper (16B) ----------------
__device__ inline void gload_lds16(const bf16* g, bf16* l) {
  __builtin_amdgcn_global_load_lds(
      (const __attribute__((address_space(1))) void*)g,
      (__attribute__((address_space(3))) void*)l, 16, 0, 0);
}

__device__ inline float softplus_f(float z) {
  // softplus(z) = max(z,0) + log1p(exp(-|z|))
  return fmaxf(z, 0.f) + __logf(1.f + __expf(-fabsf(z)));
}

// ---------------- dt GEMM: dt = softplus(Xb @ Wdb^T + bd) ----------------
// Xb [M_,K_] bf16 row-major, Wdb [D_,K_] bf16 row-major (B^T layout).
// 128x128 tile, BK=32, 256 threads = 4 waves (2x2), each wave 64x64 via 4x4 MFMA frags.
__global__ __launch_bounds__(256) void gemm_dt(const bf16* __restrict__ Xb,
                                               const bf16* __restrict__ Wdb,
                                               const float* __restrict__ bd,
                                               float* __restrict__ dt) {
  __shared__ bf16 As[128 * 32];
  __shared__ bf16 Bs[128 * 32];
  const int tid = threadIdx.x;
  const int lane = tid & 63;
  const int wave = tid >> 6;
  const int wr = wave >> 1, wc = wave & 1;
  const int mt = blockIdx.x >> 3, nt = blockIdx.x & 7;
  const int m0 = mt * 128, n0 = nt * 128;

  // staging: 512 chunks of 16B per 128x32 bf16 tile; 2 chunks per thread per tile
  const int c0 = tid, c1 = tid + 256;
  const int r0 = c0 >> 2, o0 = (c0 & 3) * 8;
  const int r1 = c1 >> 2, o1 = (c1 & 3) * 8;

  const bf16* ga0 = Xb + (size_t)(m0 + r0) * K_ + o0;
  const bf16* ga1 = Xb + (size_t)(m0 + r1) * K_ + o1;
  const bf16* gb0 = Wdb + (size_t)(n0 + r0) * K_ + o0;
  const bf16* gb1 = Wdb + (size_t)(n0 + r1) * K_ + o1;

  f32x4 acc[4][4] = {};

  const int frow = (lane & 15);        // fragment row/col within 16
  const int kg = (lane >> 4) * 8;      // k-group of 8 within BK=32

  for (int kt = 0; kt < K_; kt += 32) {
    gload_lds16(ga0 + kt, &As[c0 * 8]);
    gload_lds16(ga1 + kt, &As[c1 * 8]);
    gload_lds16(gb0 + kt, &Bs[c0 * 8]);
    gload_lds16(gb1 + kt, &Bs[c1 * 8]);
    __syncthreads();

    bf16x8 af[4], bfr[4];
#pragma unroll
    for (int i = 0; i < 4; ++i)
      af[i] = *(const bf16x8*)&As[(wr * 64 + i * 16 + frow) * 32 + kg];
#pragma unroll
    for (int i = 0; i < 4; ++i)
      bfr[i] = *(const bf16x8*)&Bs[(wc * 64 + i * 16 + frow) * 32 + kg];
#pragma unroll
    for (int i = 0; i < 4; ++i)
#pragma unroll
      for (int j = 0; j < 4; ++j)
        acc[i][j] = __builtin_amdgcn_mfma_f32_16x16x32_bf16(af[i], bfr[j], acc[i][j], 0, 0, 0);
    __syncthreads();
  }

  // epilogue: C/D layout col=lane&15, row=(lane>>4)*4+reg
  const int rbase = m0 + wr * 64 + (lane >> 4) * 4;
  const int cbase = n0 + wc * 64 + (lane & 15);
#pragma unroll
  for (int j = 0; j < 4; ++j) {
    const int col = cbase + j * 16;
    const float bias = bd[col];
#pragma unroll
    for (int i = 0; i < 4; ++i) {
      const int row = rbase + i * 16;
#pragma unroll
      for (int r = 0; r < 4; ++r) {
        float z = acc[i][j][r] + bias;
        dt[(size_t)(row + r) * D_ + col] = softplus_f(z);
      }
    }
  }
}

// ---------------- Bx = x @ Wb^T  ([M_,16]) ----------------
__global__ __launch_bounds__(256) void bx_kernel(const float* __restrict__ x,
                                                 const float* __restrict__ Wb,
                                                 float* __restrict__ Bx) {
  const int tid = threadIdx.x;
  const int rl = tid >> 4, n = tid & 15;
  const size_t row = (size_t)blockIdx.x * 16 + rl;
  const float4* xr = (const float4*)(x + row * D_);
  const float4* wr = (const float4*)(Wb + (size_t)n * D_);
  float acc = 0.f;
#pragma unroll 4
  for (int k = 0; k < D_ / 4; ++k) {
    float4 a = xr[k], w = wr[k];
    acc = fmaf(a.x, w.x, acc);
    acc = fmaf(a.y, w.y, acc);
    acc = fmaf(a.z, w.z, acc);
    acc = fmaf(a.w, w.w, acc);
  }
  Bx[row * N_ + n] = acc;
}

// ---------------- sequential scan ----------------
// block = 256 threads = 16 d x 16 n; grid = B_*(D_/16) = 512
__global__ __launch_bounds__(256) void scan_kernel(
    const float* __restrict__ dt, const float* __restrict__ Bx,
    const float* __restrict__ x, const float* __restrict__ A,
    const float* __restrict__ C, const float* __restrict__ Dp,
    float* __restrict__ out) {
  const int tid = threadIdx.x;
  const int dl = tid >> 4;   // 0..15
  const int n = tid & 15;
  const int b = blockIdx.x >> 6;          // / (D_/16)
  const int d0 = (blockIdx.x & 63) * 16;
  const int d = d0 + dl;

  const float A2 = A[d * N_ + n] * 1.44269504088896341f;  // A*log2(e) for exp2
  const float Cv = C[d * N_ + n];
  const float Dpv = Dp[d];

  const float* dtp = dt + (size_t)b * L_ * D_ + d;
  const float* xp  = x  + (size_t)b * L_ * D_ + d;
  const float* bxp = Bx + (size_t)b * L_ * N_ + n;
  float* outp = out + (size_t)b * L_ * D_ + d0;

  __shared__ float ybuf[16][16];

  float h = 0.f;

  auto step = [&](int l2, float cdt, float cbx, float cx) {
    const float a = __builtin_amdgcn_exp2f(cdt * A2);
    h = fmaf(a, h, cdt * cbx);
    float p = h * Cv;
    p += __shfl_xor(p, 1);
    p += __shfl_xor(p, 2);
    p += __shfl_xor(p, 4);
    p += __shfl_xor(p, 8);
    if (n == 0) ybuf[l2 & 15][dl] = fmaf(Dpv, cx, p);
    if ((l2 & 15) == 15) {
      __syncthreads();
      outp[(size_t)(l2 - 15 + (tid >> 4)) * D_ + (tid & 15)] = ybuf[tid >> 4][tid & 15];
      __syncthreads();
    }
  };

  // 8-deep register prefetch pipeline (statically indexed)
  float pdt[8], pbx[8], px[8];
#pragma unroll
  for (int u = 0; u < 8; ++u) {
    pdt[u] = dtp[(size_t)u * D_];
    pbx[u] = bxp[u * N_];
    px[u]  = xp[(size_t)u * D_];
  }

  int l = 0;
  for (; l < L_ - 8; l += 8) {
#pragma unroll
    for (int u = 0; u < 8; ++u) {
      const float cdt = pdt[u], cbx = pbx[u], cx = px[u];
      pdt[u] = dtp[(size_t)(l + 8 + u) * D_];
      pbx[u] = bxp[(l + 8 + u) * N_];
      px[u]  = xp[(size_t)(l + 8 + u) * D_];
      step(l + u, cdt, cbx, cx);
    }
  }
#pragma unroll
  for (int u = 0; u < 8; ++u) step(l + u, pdt[u], pbx[u], px[u]);
}

// ---------------- launch ----------------
extern "C" void kernel_launch(void* const* d_in, const int* in_sizes, int n_in,
                              void* d_out, int out_size, void* d_ws, size_t ws_size,
                              hipStream_t stream) {
  const float* x  = (const float*)d_in[0];
  const float* A  = (const float*)d_in[1];
  const float* Wb = (const float*)d_in[2];
  const float* C  = (const float*)d_in[3];
  const float* Dp = (const float*)d_in[4];
  const float* Wd = (const float*)d_in[5];
  const float* bd = (const float*)d_in[6];
  float* out = (float*)d_out;

  char* ws = (char*)d_ws;
  float* dt  = (float*)ws;                                 // 64 MB  [M_,D_] f32
  bf16*  xb  = (bf16*)(ws + (size_t)67108864);             // 32 MB  [M_,K_] bf16
  bf16*  wdb = (bf16*)(ws + (size_t)100663296);            //  2 MB  [D_,K_] bf16
  float* bx  = (float*)(ws + (size_t)102760448);           //  1 MB  [M_,16] f32

  cvt_f32_bf16<<<2048, 256, 0, stream>>>(x, xb, M_ * K_ / 4);
  cvt_f32_bf16<<<1024, 256, 0, stream>>>(Wd, wdb, D_ * K_ / 4);
  bx_kernel<<<dim3(M_ / 16), 256, 0, stream>>>(x, Wb, bx);
  gemm_dt<<<dim3((M_ / 128) * (D_ / 128)), 256, 0, stream>>>(xb, wdb, bd, dt);
  scan_kernel<<<dim3(B_ * (D_ / 16)), 256, 0, stream>>>(dt, bx, x, A, C, Dp, out);
}

// Round 2
// 333.566 us; speedup vs baseline: 1.9705x; 1.9705x over previous
//
#include <hip/hip_runtime.h>
#include <hip/hip_bf16.h>
#include <stdint.h>

#define B_ 8
#define L_ 2048
#define D_ 1024
#define N_ 16
#define M_ (B_ * L_)   // 16384 rows
#define K_ D_          // 1024
#define SEG_ 32
#define SLEN_ (L_ / SEG_)   // 64
#define LOG2E 1.44269504088896341f

typedef __bf16 bf16;
typedef __bf16 bf16x8 __attribute__((ext_vector_type(8)));
typedef float f32x4 __attribute__((ext_vector_type(4)));

// ---------------- f32 -> bf16 conversion (vectorized x4) ----------------
__global__ __launch_bounds__(256) void cvt_f32_bf16(const float* __restrict__ in,
                                                    bf16* __restrict__ out, int n4) {
  int i = blockIdx.x * 256 + threadIdx.x;
  const int stride = gridDim.x * 256;
  const float4* in4 = (const float4*)in;
  uint2* out2 = (uint2*)out;
  for (; i < n4; i += stride) {
    float4 v = in4[i];
    union { bf16 h[4]; uint2 u; } p;
    p.h[0] = (bf16)v.x; p.h[1] = (bf16)v.y; p.h[2] = (bf16)v.z; p.h[3] = (bf16)v.w;
    out2[i] = p.u;
  }
}

// ---------------- async global->LDS helper (16B) ----------------
__device__ inline void gload_lds16(const bf16* g, bf16* l) {
  __builtin_amdgcn_global_load_lds(
      (const __attribute__((address_space(1))) void*)g,
      (__attribute__((address_space(3))) void*)l, 16, 0, 0);
}

__device__ inline float softplus_f(float z) {
  return fmaxf(z, 0.f) + __logf(1.f + __expf(-fabsf(z)));
}

// ---------------- dt GEMM: dt = softplus(Xb @ Wdb^T + bd) ----------------
__global__ __launch_bounds__(256) void gemm_dt(const bf16* __restrict__ Xb,
                                               const bf16* __restrict__ Wdb,
                                               const float* __restrict__ bd,
                                               float* __restrict__ dt) {
  __shared__ bf16 As[128 * 32];
  __shared__ bf16 Bs[128 * 32];
  const int tid = threadIdx.x;
  const int lane = tid & 63;
  const int wave = tid >> 6;
  const int wr = wave >> 1, wc = wave & 1;
  const int mt = blockIdx.x >> 3, nt = blockIdx.x & 7;
  const int m0 = mt * 128, n0 = nt * 128;

  const int c0 = tid, c1 = tid + 256;
  const int r0 = c0 >> 2, o0 = (c0 & 3) * 8;
  const int r1 = c1 >> 2, o1 = (c1 & 3) * 8;

  const bf16* ga0 = Xb + (size_t)(m0 + r0) * K_ + o0;
  const bf16* ga1 = Xb + (size_t)(m0 + r1) * K_ + o1;
  const bf16* gb0 = Wdb + (size_t)(n0 + r0) * K_ + o0;
  const bf16* gb1 = Wdb + (size_t)(n0 + r1) * K_ + o1;

  f32x4 acc[4][4] = {};

  const int frow = (lane & 15);
  const int kg = (lane >> 4) * 8;

  for (int kt = 0; kt < K_; kt += 32) {
    gload_lds16(ga0 + kt, &As[c0 * 8]);
    gload_lds16(ga1 + kt, &As[c1 * 8]);
    gload_lds16(gb0 + kt, &Bs[c0 * 8]);
    gload_lds16(gb1 + kt, &Bs[c1 * 8]);
    __syncthreads();

    bf16x8 af[4], bfr[4];
#pragma unroll
    for (int i = 0; i < 4; ++i)
      af[i] = *(const bf16x8*)&As[(wr * 64 + i * 16 + frow) * 32 + kg];
#pragma unroll
    for (int i = 0; i < 4; ++i)
      bfr[i] = *(const bf16x8*)&Bs[(wc * 64 + i * 16 + frow) * 32 + kg];
#pragma unroll
    for (int i = 0; i < 4; ++i)
#pragma unroll
      for (int j = 0; j < 4; ++j)
        acc[i][j] = __builtin_amdgcn_mfma_f32_16x16x32_bf16(af[i], bfr[j], acc[i][j], 0, 0, 0);
    __syncthreads();
  }

  const int rbase = m0 + wr * 64 + (lane >> 4) * 4;
  const int cbase = n0 + wc * 64 + (lane & 15);
#pragma unroll
  for (int j = 0; j < 4; ++j) {
    const int col = cbase + j * 16;
    const float bias = bd[col];
#pragma unroll
    for (int i = 0; i < 4; ++i) {
      const int row = rbase + i * 16;
#pragma unroll
      for (int r = 0; r < 4; ++r) {
        float z = acc[i][j][r] + bias;
        dt[(size_t)(row + r) * D_ + col] = softplus_f(z);
      }
    }
  }
}

// ---------------- Bx = x @ Wb^T  ([M_,16]) ----------------
__global__ __launch_bounds__(256) void bx_kernel(const float* __restrict__ x,
                                                 const float* __restrict__ Wb,
                                                 float* __restrict__ Bx) {
  const int tid = threadIdx.x;
  const int rl = tid >> 4, n = tid & 15;
  const size_t row = (size_t)blockIdx.x * 16 + rl;
  const float4* xr = (const float4*)(x + row * D_);
  const float4* wr = (const float4*)(Wb + (size_t)n * D_);
  float acc = 0.f;
#pragma unroll 4
  for (int k = 0; k < D_ / 4; ++k) {
    float4 a = xr[k], w = wr[k];
    acc = fmaf(a.x, w.x, acc);
    acc = fmaf(a.y, w.y, acc);
    acc = fmaf(a.z, w.z, acc);
    acc = fmaf(a.w, w.w, acc);
  }
  Bx[row * N_ + n] = acc;
}

// ---------------- segmented scan, pass 1 ----------------
// thread = (b, d, seg); 16 n-states in registers. grid = B_*4*SEG_ = 1024 blocks.
// hseg layout [B_][SEG_][N_][D_], stot [B_][SEG_][D_].
__global__ __launch_bounds__(256) void scan_pass1(
    const float* __restrict__ dt, const float* __restrict__ Bx,
    const float* __restrict__ x, const float* __restrict__ A,
    const float* __restrict__ C, const float* __restrict__ Dp,
    float* __restrict__ out, float* __restrict__ hseg,
    float* __restrict__ stot) {
  const int tid = threadIdx.x;
  const int bi = blockIdx.x;
  const int seg = bi & 31;
  const int dtile = (bi >> 5) & 3;
  const int b = bi >> 7;
  const int d = dtile * 256 + tid;
  const int l0 = seg * SLEN_;

  __shared__ float bxs[SLEN_][N_];
  ((float4*)bxs)[tid] = ((const float4*)(Bx + ((size_t)b * L_ + l0) * N_))[tid];

  float A2[N_], Cv[N_];
  {
    const float4* ap = (const float4*)(A + (size_t)d * N_);
    const float4* cp = (const float4*)(C + (size_t)d * N_);
#pragma unroll
    for (int q = 0; q < 4; ++q) {
      float4 a = ap[q], c = cp[q];
      A2[q * 4 + 0] = a.x * LOG2E; A2[q * 4 + 1] = a.y * LOG2E;
      A2[q * 4 + 2] = a.z * LOG2E; A2[q * 4 + 3] = a.w * LOG2E;
      Cv[q * 4 + 0] = c.x; Cv[q * 4 + 1] = c.y;
      Cv[q * 4 + 2] = c.z; Cv[q * 4 + 3] = c.w;
    }
  }
  const float Dpv = Dp[d];

  const size_t base = ((size_t)b * L_ + l0) * D_ + d;
  const float* dtp = dt + base;
  const float* xp = x + base;
  float* op = out + base;

  float h[N_] = {};
  float s = 0.f;
  __syncthreads();

  float cdt = dtp[0], cx = xp[0];
#pragma unroll 2
  for (int i = 0; i < SLEN_; ++i) {
    const int ip = (i + 1 < SLEN_) ? i + 1 : i;
    const float ndt = dtp[(size_t)ip * D_];
    const float nx = xp[(size_t)ip * D_];
    s += cdt;
    float y = Dpv * cx;
#pragma unroll
    for (int q = 0; q < 4; ++q) {
      const float4 bv = ((const float4*)bxs[i])[q];
      const float bvf[4] = {bv.x, bv.y, bv.z, bv.w};
#pragma unroll
      for (int j = 0; j < 4; ++j) {
        const int n = q * 4 + j;
        const float e = __builtin_amdgcn_exp2f(cdt * A2[n]);
        h[n] = fmaf(e, h[n], cdt * bvf[j]);
        y = fmaf(h[n], Cv[n], y);
      }
    }
    op[(size_t)i * D_] = y;
    cdt = ndt; cx = nx;
  }

  float* hp = hseg + (((size_t)b * SEG_ + seg) * N_) * D_ + d;
#pragma unroll
  for (int n = 0; n < N_; ++n) hp[(size_t)n * D_] = h[n];
  stot[((size_t)b * SEG_ + seg) * D_ + d] = s;
}

// ---------------- pass 2: combine segments (in-place hseg -> h0 per segment) ----
__global__ __launch_bounds__(256) void scan_combine(
    const float* __restrict__ A, float* __restrict__ hseg,
    const float* __restrict__ stot) {
  const int tid = threadIdx.x;
  const int bi = blockIdx.x;          // B_ * (D_/16) = 512
  const int b = bi >> 6;
  const int d = (bi & 63) * 16 + (tid >> 4);
  const int n = tid & 15;
  const float A2 = A[(size_t)d * N_ + n] * LOG2E;
  float g = 0.f;
  for (int sg = 0; sg < SEG_; ++sg) {
    const size_t ho = (((size_t)b * SEG_ + sg) * N_ + n) * D_ + d;
    const float hs = hseg[ho];
    const float st = stot[((size_t)b * SEG_ + sg) * D_ + d];
    hseg[ho] = g;
    g = fmaf(__builtin_amdgcn_exp2f(A2 * st), g, hs);
  }
}

// ---------------- pass 3: add C . exp(A*cumsum)*h0 correction ----------------
__global__ __launch_bounds__(256) void scan_fix(
    const float* __restrict__ dt, const float* __restrict__ A,
    const float* __restrict__ C, const float* __restrict__ hseg,
    float* __restrict__ out) {
  const int tid = threadIdx.x;
  const int bi = blockIdx.x;          // B_*4*(SEG_-1) = 992
  const int b = bi / 124;
  const int r = bi - b * 124;
  const int dtile = r / 31;
  const int seg = 1 + (r - dtile * 31);
  const int d = dtile * 256 + tid;
  const int l0 = seg * SLEN_;

  float A2[N_], CG[N_];
  {
    const float4* ap = (const float4*)(A + (size_t)d * N_);
    const float4* cp = (const float4*)(C + (size_t)d * N_);
    const float* hp = hseg + (((size_t)b * SEG_ + seg) * N_) * D_ + d;
#pragma unroll
    for (int q = 0; q < 4; ++q) {
      float4 a = ap[q], c = cp[q];
      A2[q * 4 + 0] = a.x * LOG2E; A2[q * 4 + 1] = a.y * LOG2E;
      A2[q * 4 + 2] = a.z * LOG2E; A2[q * 4 + 3] = a.w * LOG2E;
      CG[q * 4 + 0] = c.x * hp[(size_t)(q * 4 + 0) * D_];
      CG[q * 4 + 1] = c.y * hp[(size_t)(q * 4 + 1) * D_];
      CG[q * 4 + 2] = c.z * hp[(size_t)(q * 4 + 2) * D_];
      CG[q * 4 + 3] = c.w * hp[(size_t)(q * 4 + 3) * D_];
    }
  }

  const size_t base = ((size_t)b * L_ + l0) * D_ + d;
  const float* dtp = dt + base;
  float* op = out + base;

  float s = 0.f;
  float cdt = dtp[0];
#pragma unroll 2
  for (int i = 0; i < SLEN_; ++i) {
    const int ip = (i + 1 < SLEN_) ? i + 1 : i;
    const float ndt = dtp[(size_t)ip * D_];
    s += cdt;
    float acc = 0.f;
#pragma unroll
    for (int n = 0; n < N_; ++n)
      acc = fmaf(__builtin_amdgcn_exp2f(s * A2[n]), CG[n], acc);
    op[(size_t)i * D_] += acc;
    cdt = ndt;
  }
}

// ---------------- launch ----------------
extern "C" void kernel_launch(void* const* d_in, const int* in_sizes, int n_in,
                              void* d_out, int out_size, void* d_ws, size_t ws_size,
                              hipStream_t stream) {
  const float* x  = (const float*)d_in[0];
  const float* A  = (const float*)d_in[1];
  const float* Wb = (const float*)d_in[2];
  const float* C  = (const float*)d_in[3];
  const float* Dp = (const float*)d_in[4];
  const float* Wd = (const float*)d_in[5];
  const float* bd = (const float*)d_in[6];
  float* out = (float*)d_out;

  char* ws = (char*)d_ws;
  float* dt  = (float*)ws;                                 // 64 MB  [M_,D_]
  bf16*  xb  = (bf16*)(ws + (size_t)67108864);             // 32 MB  (dead after gemm)
  bf16*  wdb = (bf16*)(ws + (size_t)100663296);            //  2 MB
  float* bx  = (float*)(ws + (size_t)102760448);           //  1 MB
  // reuse xb region after gemm:
  float* hseg = (float*)(ws + (size_t)67108864);           // 16 MB [B][SEG][N][D]
  float* stot = (float*)(ws + (size_t)(67108864 + 16777216)); // 1 MB [B][SEG][D]

  cvt_f32_bf16<<<2048, 256, 0, stream>>>(x, xb, M_ * K_ / 4);
  cvt_f32_bf16<<<1024, 256, 0, stream>>>(Wd, wdb, D_ * K_ / 4);
  bx_kernel<<<dim3(M_ / 16), 256, 0, stream>>>(x, Wb, bx);
  gemm_dt<<<dim3((M_ / 128) * (D_ / 128)), 256, 0, stream>>>(xb, wdb, bd, dt);
  scan_pass1<<<dim3(B_ * 4 * SEG_), 256, 0, stream>>>(dt, bx, x, A, C, Dp, out, hseg, stot);
  scan_combine<<<dim3(B_ * (D_ / 16)), 256, 0, stream>>>(A, hseg, stot);
  scan_fix<<<dim3(B_ * 4 * (SEG_ - 1)), 256, 0, stream>>>(dt, A, C, hseg, out);
}

// Round 3
// 207.506 us; speedup vs baseline: 3.1676x; 1.6075x over previous
//
#include <hip/hip_runtime.h>
#include <hip/hip_bf16.h>
#include <stdint.h>

#define B_ 8
#define L_ 2048
#define D_ 1024
#define N_ 16
#define M_ (B_ * L_)   // 16384 rows
#define K_ D_          // 1024
#define SEG_ 32
#define SLEN_ (L_ / SEG_)   // 64
#define LOG2E 1.44269504088896341f

typedef __bf16 bf16;
typedef __bf16 bf16x8 __attribute__((ext_vector_type(8)));
typedef float f32x4 __attribute__((ext_vector_type(4)));

// ---------------- f32 -> bf16 conversion (vectorized x4) ----------------
__global__ __launch_bounds__(256) void cvt_f32_bf16(const float* __restrict__ in,
                                                    bf16* __restrict__ out, int n4) {
  int i = blockIdx.x * 256 + threadIdx.x;
  const int stride = gridDim.x * 256;
  const float4* in4 = (const float4*)in;
  uint2* out2 = (uint2*)out;
  for (; i < n4; i += stride) {
    float4 v = in4[i];
    union { bf16 h[4]; uint2 u; } p;
    p.h[0] = (bf16)v.x; p.h[1] = (bf16)v.y; p.h[2] = (bf16)v.z; p.h[3] = (bf16)v.w;
    out2[i] = p.u;
  }
}

// ---------------- async global->LDS helper (16B) ----------------
__device__ inline void gload_lds16(const bf16* g, bf16* l) {
  __builtin_amdgcn_global_load_lds(
      (const __attribute__((address_space(1))) void*)g,
      (__attribute__((address_space(3))) void*)l, 16, 0, 0);
}

__device__ inline float softplus_f(float z) {
  return fmaxf(z, 0.f) + __logf(1.f + __expf(-fabsf(z)));
}

// ---------------- dt GEMM: dt = softplus(Xb @ Wdb^T + bd) ----------------
__global__ __launch_bounds__(256) void gemm_dt(const bf16* __restrict__ Xb,
                                               const bf16* __restrict__ Wdb,
                                               const float* __restrict__ bd,
                                               float* __restrict__ dt) {
  __shared__ bf16 As[128 * 32];
  __shared__ bf16 Bs[128 * 32];
  const int tid = threadIdx.x;
  const int lane = tid & 63;
  const int wave = tid >> 6;
  const int wr = wave >> 1, wc = wave & 1;
  const int mt = blockIdx.x >> 3, nt = blockIdx.x & 7;
  const int m0 = mt * 128, n0 = nt * 128;

  const int c0 = tid, c1 = tid + 256;
  const int r0 = c0 >> 2, o0 = (c0 & 3) * 8;
  const int r1 = c1 >> 2, o1 = (c1 & 3) * 8;

  const bf16* ga0 = Xb + (size_t)(m0 + r0) * K_ + o0;
  const bf16* ga1 = Xb + (size_t)(m0 + r1) * K_ + o1;
  const bf16* gb0 = Wdb + (size_t)(n0 + r0) * K_ + o0;
  const bf16* gb1 = Wdb + (size_t)(n0 + r1) * K_ + o1;

  f32x4 acc[4][4] = {};

  const int frow = (lane & 15);
  const int kg = (lane >> 4) * 8;

  for (int kt = 0; kt < K_; kt += 32) {
    gload_lds16(ga0 + kt, &As[c0 * 8]);
    gload_lds16(ga1 + kt, &As[c1 * 8]);
    gload_lds16(gb0 + kt, &Bs[c0 * 8]);
    gload_lds16(gb1 + kt, &Bs[c1 * 8]);
    __syncthreads();

    bf16x8 af[4], bfr[4];
#pragma unroll
    for (int i = 0; i < 4; ++i)
      af[i] = *(const bf16x8*)&As[(wr * 64 + i * 16 + frow) * 32 + kg];
#pragma unroll
    for (int i = 0; i < 4; ++i)
      bfr[i] = *(const bf16x8*)&Bs[(wc * 64 + i * 16 + frow) * 32 + kg];
#pragma unroll
    for (int i = 0; i < 4; ++i)
#pragma unroll
      for (int j = 0; j < 4; ++j)
        acc[i][j] = __builtin_amdgcn_mfma_f32_16x16x32_bf16(af[i], bfr[j], acc[i][j], 0, 0, 0);
    __syncthreads();
  }

  const int rbase = m0 + wr * 64 + (lane >> 4) * 4;
  const int cbase = n0 + wc * 64 + (lane & 15);
#pragma unroll
  for (int j = 0; j < 4; ++j) {
    const int col = cbase + j * 16;
    const float bias = bd[col];
#pragma unroll
    for (int i = 0; i < 4; ++i) {
      const int row = rbase + i * 16;
#pragma unroll
      for (int r = 0; r < 4; ++r) {
        float z = acc[i][j][r] + bias;
        dt[(size_t)(row + r) * D_ + col] = softplus_f(z);
      }
    }
  }
}

// ---------------- Bx = x @ Wb^T via MFMA ([M_,16]) ----------------
// 1 wave -> 16 rows x 16 cols. 4 waves/block -> 64 rows/block. 256 blocks.
__global__ __launch_bounds__(256) void bx_mfma(const bf16* __restrict__ Xb,
                                               const bf16* __restrict__ Wbb,
                                               float* __restrict__ Bx) {
  const int lane = threadIdx.x & 63;
  const int wave = threadIdx.x >> 6;
  const int row0 = blockIdx.x * 64 + wave * 16;
  const int fr = lane & 15;
  const int kg = (lane >> 4) * 8;
  const bf16* ga = Xb + (size_t)(row0 + fr) * K_ + kg;
  const bf16* gb = Wbb + (size_t)fr * K_ + kg;
  f32x4 acc = {};
#pragma unroll 8
  for (int kt = 0; kt < K_; kt += 32) {
    bf16x8 af = *(const bf16x8*)(ga + kt);
    bf16x8 bf = *(const bf16x8*)(gb + kt);
    acc = __builtin_amdgcn_mfma_f32_16x16x32_bf16(af, bf, acc, 0, 0, 0);
  }
  const int orow = row0 + (lane >> 4) * 4;
  const int ocol = lane & 15;
#pragma unroll
  for (int r = 0; r < 4; ++r)
    Bx[(size_t)(orow + r) * N_ + ocol] = acc[r];
}

// ---------------- segmented scan, pass 1 ----------------
// thread = (b, d, seg); 16 n-states in registers. grid = B_*4*SEG_ = 1024 blocks.
// hseg layout [B_][SEG_][N_][D_], stot [B_][SEG_][D_].
__global__ __launch_bounds__(256) void scan_pass1(
    const float* __restrict__ dt, const float* __restrict__ Bx,
    const float* __restrict__ x, const float* __restrict__ A,
    const float* __restrict__ C, const float* __restrict__ Dp,
    float* __restrict__ out, float* __restrict__ hseg,
    float* __restrict__ stot) {
  const int tid = threadIdx.x;
  const int bi = blockIdx.x;
  const int seg = bi & 31;
  const int dtile = (bi >> 5) & 3;
  const int b = bi >> 7;
  const int d = dtile * 256 + tid;
  const int l0 = seg * SLEN_;

  __shared__ float bxs[SLEN_][N_];
  ((float4*)bxs)[tid] = ((const float4*)(Bx + ((size_t)b * L_ + l0) * N_))[tid];

  float A2[N_], Cv[N_];
  {
    const float4* ap = (const float4*)(A + (size_t)d * N_);
    const float4* cp = (const float4*)(C + (size_t)d * N_);
#pragma unroll
    for (int q = 0; q < 4; ++q) {
      float4 a = ap[q], c = cp[q];
      A2[q * 4 + 0] = a.x * LOG2E; A2[q * 4 + 1] = a.y * LOG2E;
      A2[q * 4 + 2] = a.z * LOG2E; A2[q * 4 + 3] = a.w * LOG2E;
      Cv[q * 4 + 0] = c.x; Cv[q * 4 + 1] = c.y;
      Cv[q * 4 + 2] = c.z; Cv[q * 4 + 3] = c.w;
    }
  }
  const float Dpv = Dp[d];

  const size_t base = ((size_t)b * L_ + l0) * D_ + d;
  const float* dtp = dt + base;
  const float* xp = x + base;
  float* op = out + base;

  float h[N_] = {};
  float s = 0.f;
  __syncthreads();

  float cdt = dtp[0], cx = xp[0];
#pragma unroll 2
  for (int i = 0; i < SLEN_; ++i) {
    const int ip = (i + 1 < SLEN_) ? i + 1 : i;
    const float ndt = dtp[(size_t)ip * D_];
    const float nx = xp[(size_t)ip * D_];
    s += cdt;
    float y = Dpv * cx;
#pragma unroll
    for (int q = 0; q < 4; ++q) {
      const float4 bv = ((const float4*)bxs[i])[q];
      const float bvf[4] = {bv.x, bv.y, bv.z, bv.w};
#pragma unroll
      for (int j = 0; j < 4; ++j) {
        const int n = q * 4 + j;
        const float e = __builtin_amdgcn_exp2f(cdt * A2[n]);
        h[n] = fmaf(e, h[n], cdt * bvf[j]);
        y = fmaf(h[n], Cv[n], y);
      }
    }
    op[(size_t)i * D_] = y;
    cdt = ndt; cx = nx;
  }

  float* hp = hseg + (((size_t)b * SEG_ + seg) * N_) * D_ + d;
#pragma unroll
  for (int n = 0; n < N_; ++n) hp[(size_t)n * D_] = h[n];
  stot[((size_t)b * SEG_ + seg) * D_ + d] = s;
}

// ---------------- pass 2: combine segments (in-place hseg -> h0 per segment) ----
__global__ __launch_bounds__(256) void scan_combine(
    const float* __restrict__ A, float* __restrict__ hseg,
    const float* __restrict__ stot) {
  const int tid = threadIdx.x;
  const int bi = blockIdx.x;          // B_ * (D_/16) = 512
  const int b = bi >> 6;
  const int d = (bi & 63) * 16 + (tid >> 4);
  const int n = tid & 15;
  const float A2 = A[(size_t)d * N_ + n] * LOG2E;
  float g = 0.f;
  for (int sg = 0; sg < SEG_; ++sg) {
    const size_t ho = (((size_t)b * SEG_ + sg) * N_ + n) * D_ + d;
    const float hs = hseg[ho];
    const float st = stot[((size_t)b * SEG_ + sg) * D_ + d];
    hseg[ho] = g;
    g = fmaf(__builtin_amdgcn_exp2f(A2 * st), g, hs);
  }
}

// ---------------- pass 3: add C . exp(A*cumsum)*h0 correction ----------------
__global__ __launch_bounds__(256) void scan_fix(
    const float* __restrict__ dt, const float* __restrict__ A,
    const float* __restrict__ C, const float* __restrict__ hseg,
    float* __restrict__ out) {
  const int tid = threadIdx.x;
  const int bi = blockIdx.x;          // B_*4*(SEG_-1) = 992
  const int b = bi / 124;
  const int r = bi - b * 124;
  const int dtile = r / 31;
  const int seg = 1 + (r - dtile * 31);
  const int d = dtile * 256 + tid;
  const int l0 = seg * SLEN_;

  float A2[N_], CG[N_];
  {
    const float4* ap = (const float4*)(A + (size_t)d * N_);
    const float4* cp = (const float4*)(C + (size_t)d * N_);
    const float* hp = hseg + (((size_t)b * SEG_ + seg) * N_) * D_ + d;
#pragma unroll
    for (int q = 0; q < 4; ++q) {
      float4 a = ap[q], c = cp[q];
      A2[q * 4 + 0] = a.x * LOG2E; A2[q * 4 + 1] = a.y * LOG2E;
      A2[q * 4 + 2] = a.z * LOG2E; A2[q * 4 + 3] = a.w * LOG2E;
      CG[q * 4 + 0] = c.x * hp[(size_t)(q * 4 + 0) * D_];
      CG[q * 4 + 1] = c.y * hp[(size_t)(q * 4 + 1) * D_];
      CG[q * 4 + 2] = c.z * hp[(size_t)(q * 4 + 2) * D_];
      CG[q * 4 + 3] = c.w * hp[(size_t)(q * 4 + 3) * D_];
    }
  }

  const size_t base = ((size_t)b * L_ + l0) * D_ + d;
  const float* dtp = dt + base;
  float* op = out + base;

  float s = 0.f;
  float cdt = dtp[0];
#pragma unroll 2
  for (int i = 0; i < SLEN_; ++i) {
    const int ip = (i + 1 < SLEN_) ? i + 1 : i;
    const float ndt = dtp[(size_t)ip * D_];
    s += cdt;
    float acc = 0.f;
#pragma unroll
    for (int n = 0; n < N_; ++n)
      acc = fmaf(__builtin_amdgcn_exp2f(s * A2[n]), CG[n], acc);
    op[(size_t)i * D_] += acc;
    cdt = ndt;
  }
}

// ---------------- launch ----------------
extern "C" void kernel_launch(void* const* d_in, const int* in_sizes, int n_in,
                              void* d_out, int out_size, void* d_ws, size_t ws_size,
                              hipStream_t stream) {
  const float* x  = (const float*)d_in[0];
  const float* A  = (const float*)d_in[1];
  const float* Wb = (const float*)d_in[2];
  const float* C  = (const float*)d_in[3];
  const float* Dp = (const float*)d_in[4];
  const float* Wd = (const float*)d_in[5];
  const float* bd = (const float*)d_in[6];
  float* out = (float*)d_out;

  char* ws = (char*)d_ws;
  float* dt  = (float*)ws;                                 // 64 MB  [M_,D_]
  bf16*  xb  = (bf16*)(ws + (size_t)67108864);             // 32 MB  (dead after gemm+bx)
  bf16*  wdb = (bf16*)(ws + (size_t)100663296);            //  2 MB
  float* bx  = (float*)(ws + (size_t)102760448);           //  1 MB
  bf16*  wbb = (bf16*)(ws + (size_t)103809024);            // 32 KB [16][1024] bf16
  // reuse xb region after gemm/bx:
  float* hseg = (float*)(ws + (size_t)67108864);           // 16 MB [B][SEG][N][D]
  float* stot = (float*)(ws + (size_t)(67108864 + 16777216)); // 1 MB [B][SEG][D]

  cvt_f32_bf16<<<2048, 256, 0, stream>>>(x, xb, M_ * K_ / 4);
  cvt_f32_bf16<<<1024, 256, 0, stream>>>(Wd, wdb, D_ * K_ / 4);
  cvt_f32_bf16<<<16, 256, 0, stream>>>(Wb, wbb, N_ * K_ / 4);
  bx_mfma<<<dim3(M_ / 64), 256, 0, stream>>>(xb, wbb, bx);
  gemm_dt<<<dim3((M_ / 128) * (D_ / 128)), 256, 0, stream>>>(xb, wdb, bd, dt);
  scan_pass1<<<dim3(B_ * 4 * SEG_), 256, 0, stream>>>(dt, bx, x, A, C, Dp, out, hseg, stot);
  scan_combine<<<dim3(B_ * (D_ / 16)), 256, 0, stream>>>(A, hseg, stot);
  scan_fix<<<dim3(B_ * 4 * (SEG_ - 1)), 256, 0, stream>>>(dt, A, C, hseg, out);
}

// Round 4
// 201.617 us; speedup vs baseline: 3.2602x; 1.0292x over previous
//
#include <hip/hip_runtime.h>
#include <hip/hip_bf16.h>
#include <stdint.h>

#define B_ 8
#define L_ 2048
#define D_ 1024
#define N_ 16
#define M_ (B_ * L_)   // 16384 rows
#define K_ D_          // 1024
#define SEG_ 32
#define SLEN_ (L_ / SEG_)   // 64
#define LOG2E 1.44269504088896341f

typedef __bf16 bf16;
typedef __bf16 bf16x8 __attribute__((ext_vector_type(8)));
typedef float f32x4 __attribute__((ext_vector_type(4)));

// ---------------- f32 -> bf16 conversion (vectorized x4) ----------------
__global__ __launch_bounds__(256) void cvt_f32_bf16(const float* __restrict__ in,
                                                    bf16* __restrict__ out, int n4) {
  int i = blockIdx.x * 256 + threadIdx.x;
  const int stride = gridDim.x * 256;
  const float4* in4 = (const float4*)in;
  uint2* out2 = (uint2*)out;
  for (; i < n4; i += stride) {
    float4 v = in4[i];
    union { bf16 h[4]; uint2 u; } p;
    p.h[0] = (bf16)v.x; p.h[1] = (bf16)v.y; p.h[2] = (bf16)v.z; p.h[3] = (bf16)v.w;
    out2[i] = p.u;
  }
}

// ---------------- async global->LDS helper (16B) ----------------
__device__ inline void gload_lds16(const bf16* g, bf16* l) {
  __builtin_amdgcn_global_load_lds(
      (const __attribute__((address_space(1))) void*)g,
      (__attribute__((address_space(3))) void*)l, 16, 0, 0);
}

__device__ inline float softplus_f(float z) {
  return fmaxf(z, 0.f) + __logf(1.f + __expf(-fabsf(z)));
}

// ---------------- dt GEMM: dtb = bf16(softplus(Xb @ Wdb^T + bd)) ----------------
// 128x128 tile, BK=64, 256 threads = 4 waves (2x2). XCD-chunked block swizzle.
__global__ __launch_bounds__(256) void gemm_dt(const bf16* __restrict__ Xb,
                                               const bf16* __restrict__ Wdb,
                                               const float* __restrict__ bd,
                                               bf16* __restrict__ dtb) {
  __shared__ bf16 As[128 * 64];
  __shared__ bf16 Bs[128 * 64];
  const int tid = threadIdx.x;
  const int lane = tid & 63;
  const int wave = tid >> 6;
  const int wr = wave >> 1, wc = wave & 1;
  // XCD swizzle: grid 1024 (128 mt x 8 nt), 8 XCDs, 1024%8==0 -> bijective.
  // xcd = bid%8 gets virt in [xcd*128, xcd*128+128) = 16 consecutive m-panels.
  const int virt = (blockIdx.x & 7) * 128 + (blockIdx.x >> 3);
  const int mt = virt >> 3, nt = virt & 7;
  const int m0 = mt * 128, n0 = nt * 128;

  // staging: 128x64 bf16 tile = 1024 chunks of 16B; 4 chunks/thread/matrix
  const bf16* ga[4];
  const bf16* gb[4];
#pragma unroll
  for (int q = 0; q < 4; ++q) {
    const int cc = tid + 256 * q;
    const int row = cc >> 3, off = (cc & 7) * 8;
    ga[q] = Xb + (size_t)(m0 + row) * K_ + off;
    gb[q] = Wdb + (size_t)(n0 + row) * K_ + off;
  }

  f32x4 acc[4][4] = {};
  const int frow = (lane & 15);
  const int kg = (lane >> 4) * 8;

  for (int kt = 0; kt < K_; kt += 64) {
#pragma unroll
    for (int q = 0; q < 4; ++q) {
      gload_lds16(ga[q] + kt, &As[(tid + 256 * q) * 8]);
      gload_lds16(gb[q] + kt, &Bs[(tid + 256 * q) * 8]);
    }
    __syncthreads();
#pragma unroll
    for (int ks = 0; ks < 2; ++ks) {
      bf16x8 af[4], bfr[4];
#pragma unroll
      for (int i = 0; i < 4; ++i)
        af[i] = *(const bf16x8*)&As[(wr * 64 + i * 16 + frow) * 64 + ks * 32 + kg];
#pragma unroll
      for (int i = 0; i < 4; ++i)
        bfr[i] = *(const bf16x8*)&Bs[(wc * 64 + i * 16 + frow) * 64 + ks * 32 + kg];
#pragma unroll
      for (int i = 0; i < 4; ++i)
#pragma unroll
        for (int j = 0; j < 4; ++j)
          acc[i][j] = __builtin_amdgcn_mfma_f32_16x16x32_bf16(af[i], bfr[j], acc[i][j], 0, 0, 0);
    }
    __syncthreads();
  }

  const int rbase = m0 + wr * 64 + (lane >> 4) * 4;
  const int cbase = n0 + wc * 64 + (lane & 15);
#pragma unroll
  for (int j = 0; j < 4; ++j) {
    const int col = cbase + j * 16;
    const float bias = bd[col];
#pragma unroll
    for (int i = 0; i < 4; ++i) {
      const int row = rbase + i * 16;
#pragma unroll
      for (int r = 0; r < 4; ++r) {
        float z = acc[i][j][r] + bias;
        dtb[(size_t)(row + r) * D_ + col] = (bf16)softplus_f(z);
      }
    }
  }
}

// ---------------- Bx = x @ Wb^T via MFMA ([M_,16]) ----------------
__global__ __launch_bounds__(256) void bx_mfma(const bf16* __restrict__ Xb,
                                               const bf16* __restrict__ Wbb,
                                               float* __restrict__ Bx) {
  const int lane = threadIdx.x & 63;
  const int wave = threadIdx.x >> 6;
  const int row0 = blockIdx.x * 64 + wave * 16;
  const int fr = lane & 15;
  const int kg = (lane >> 4) * 8;
  const bf16* ga = Xb + (size_t)(row0 + fr) * K_ + kg;
  const bf16* gb = Wbb + (size_t)fr * K_ + kg;
  f32x4 acc = {};
#pragma unroll 8
  for (int kt = 0; kt < K_; kt += 32) {
    bf16x8 af = *(const bf16x8*)(ga + kt);
    bf16x8 bf = *(const bf16x8*)(gb + kt);
    acc = __builtin_amdgcn_mfma_f32_16x16x32_bf16(af, bf, acc, 0, 0, 0);
  }
  const int orow = row0 + (lane >> 4) * 4;
  const int ocol = lane & 15;
#pragma unroll
  for (int r = 0; r < 4; ++r)
    Bx[(size_t)(orow + r) * N_ + ocol] = acc[r];
}

// ---------------- pass 1: per-segment summaries only ----------------
// thread = (b, d, seg). grid = B_*4*SEG_ = 1024. hseg [B][SEG][D][N], stot [B][SEG][D].
__global__ __launch_bounds__(256) void scan_p1(
    const bf16* __restrict__ dtb, const float* __restrict__ Bx,
    const float* __restrict__ A, float* __restrict__ hseg,
    float* __restrict__ stot) {
  const int tid = threadIdx.x;
  const int bi = blockIdx.x;
  const int seg = bi & 31;
  const int dtile = (bi >> 5) & 3;
  const int b = bi >> 7;
  const int d = dtile * 256 + tid;
  const int l0 = seg * SLEN_;

  __shared__ float bxs[SLEN_][N_];
  ((float4*)bxs)[tid] = ((const float4*)(Bx + ((size_t)b * L_ + l0) * N_))[tid];

  float A2[N_];
  {
    const float4* ap = (const float4*)(A + (size_t)d * N_);
#pragma unroll
    for (int q = 0; q < 4; ++q) {
      float4 a = ap[q];
      A2[q * 4 + 0] = a.x * LOG2E; A2[q * 4 + 1] = a.y * LOG2E;
      A2[q * 4 + 2] = a.z * LOG2E; A2[q * 4 + 3] = a.w * LOG2E;
    }
  }

  const bf16* dtp = dtb + ((size_t)b * L_ + l0) * D_ + d;
  float h[N_] = {};
  float s = 0.f;
  __syncthreads();

  float cdt = (float)dtp[0];
#pragma unroll 4
  for (int i = 0; i < SLEN_; ++i) {
    const int ip = (i + 1 < SLEN_) ? i + 1 : i;
    const float ndt = (float)dtp[(size_t)ip * D_];
    s += cdt;
#pragma unroll
    for (int q = 0; q < 4; ++q) {
      const float4 bv = ((const float4*)bxs[i])[q];
      const float bvf[4] = {bv.x, bv.y, bv.z, bv.w};
#pragma unroll
      for (int j = 0; j < 4; ++j) {
        const int n = q * 4 + j;
        const float e = __builtin_amdgcn_exp2f(cdt * A2[n]);
        h[n] = fmaf(e, h[n], cdt * bvf[j]);
      }
    }
    cdt = ndt;
  }

  float* hp = hseg + (((size_t)b * SEG_ + seg) * D_ + d) * N_;
#pragma unroll
  for (int q = 0; q < 4; ++q)
    ((float4*)hp)[q] = (float4){h[q * 4], h[q * 4 + 1], h[q * 4 + 2], h[q * 4 + 3]};
  stot[((size_t)b * SEG_ + seg) * D_ + d] = s;
}

// ---------------- pass 2: exclusive-prefix combine (in-place hseg -> h0) ----
__global__ __launch_bounds__(256) void scan_combine(
    const float* __restrict__ A, float* __restrict__ hseg,
    const float* __restrict__ stot) {
  const int tid = threadIdx.x;
  const int bi = blockIdx.x;          // B_ * (D_/16) = 512
  const int b = bi >> 6;
  const int d = (bi & 63) * 16 + (tid >> 4);
  const int n = tid & 15;
  const float A2 = A[(size_t)d * N_ + n] * LOG2E;
  float g = 0.f;
  for (int sg = 0; sg < SEG_; ++sg) {
    const size_t ho = (((size_t)b * SEG_ + sg) * D_ + d) * N_ + n;
    const float hs = hseg[ho];
    const float st = stot[((size_t)b * SEG_ + sg) * D_ + d];
    hseg[ho] = g;
    g = fmaf(__builtin_amdgcn_exp2f(A2 * st), g, hs);
  }
}

// ---------------- pass 3: full recurrence from h0, single out write ----------
__global__ __launch_bounds__(256) void scan_p3(
    const bf16* __restrict__ dtb, const float* __restrict__ Bx,
    const bf16* __restrict__ xb, const float* __restrict__ A,
    const float* __restrict__ C, const float* __restrict__ Dp,
    const float* __restrict__ hseg, float* __restrict__ out) {
  const int tid = threadIdx.x;
  const int bi = blockIdx.x;
  const int seg = bi & 31;
  const int dtile = (bi >> 5) & 3;
  const int b = bi >> 7;
  const int d = dtile * 256 + tid;
  const int l0 = seg * SLEN_;

  __shared__ float bxs[SLEN_][N_];
  ((float4*)bxs)[tid] = ((const float4*)(Bx + ((size_t)b * L_ + l0) * N_))[tid];

  float A2[N_], Cv[N_], h[N_];
  {
    const float4* ap = (const float4*)(A + (size_t)d * N_);
    const float4* cp = (const float4*)(C + (size_t)d * N_);
    const float4* hp = (const float4*)(hseg + (((size_t)b * SEG_ + seg) * D_ + d) * N_);
#pragma unroll
    for (int q = 0; q < 4; ++q) {
      float4 a = ap[q], c = cp[q], hh = hp[q];
      A2[q * 4 + 0] = a.x * LOG2E; A2[q * 4 + 1] = a.y * LOG2E;
      A2[q * 4 + 2] = a.z * LOG2E; A2[q * 4 + 3] = a.w * LOG2E;
      Cv[q * 4 + 0] = c.x; Cv[q * 4 + 1] = c.y;
      Cv[q * 4 + 2] = c.z; Cv[q * 4 + 3] = c.w;
      h[q * 4 + 0] = hh.x; h[q * 4 + 1] = hh.y;
      h[q * 4 + 2] = hh.z; h[q * 4 + 3] = hh.w;
    }
  }
  const float Dpv = Dp[d];

  const size_t base = ((size_t)b * L_ + l0) * D_ + d;
  const bf16* dtp = dtb + base;
  const bf16* xp = xb + base;
  float* op = out + base;
  __syncthreads();

  float cdt = (float)dtp[0];
  float cx = (float)xp[0];
#pragma unroll 4
  for (int i = 0; i < SLEN_; ++i) {
    const int ip = (i + 1 < SLEN_) ? i + 1 : i;
    const float ndt = (float)dtp[(size_t)ip * D_];
    const float nx = (float)xp[(size_t)ip * D_];
    float y = Dpv * cx;
#pragma unroll
    for (int q = 0; q < 4; ++q) {
      const float4 bv = ((const float4*)bxs[i])[q];
      const float bvf[4] = {bv.x, bv.y, bv.z, bv.w};
#pragma unroll
      for (int j = 0; j < 4; ++j) {
        const int n = q * 4 + j;
        const float e = __builtin_amdgcn_exp2f(cdt * A2[n]);
        h[n] = fmaf(e, h[n], cdt * bvf[j]);
        y = fmaf(h[n], Cv[n], y);
      }
    }
    op[(size_t)i * D_] = y;
    cdt = ndt; cx = nx;
  }
}

// ---------------- launch ----------------
extern "C" void kernel_launch(void* const* d_in, const int* in_sizes, int n_in,
                              void* d_out, int out_size, void* d_ws, size_t ws_size,
                              hipStream_t stream) {
  const float* x  = (const float*)d_in[0];
  const float* A  = (const float*)d_in[1];
  const float* Wb = (const float*)d_in[2];
  const float* C  = (const float*)d_in[3];
  const float* Dp = (const float*)d_in[4];
  const float* Wd = (const float*)d_in[5];
  const float* bd = (const float*)d_in[6];
  float* out = (float*)d_out;

  char* ws = (char*)d_ws;
  bf16*  dtb  = (bf16*)ws;                                  // 32 MB [M,D] bf16
  bf16*  xb   = (bf16*)(ws + (size_t)33554432);             // 32 MB [M,K] bf16
  bf16*  wdb  = (bf16*)(ws + (size_t)67108864);             //  2 MB [D,K] bf16
  bf16*  wbb  = (bf16*)(ws + (size_t)69206016);             // 32 KB [16,K] bf16
  float* bx   = (float*)(ws + (size_t)70254592);            //  1 MB [M,16] f32
  float* hseg = (float*)(ws + (size_t)71303168);            // 16 MB [B][SEG][D][N]
  float* stot = (float*)(ws + (size_t)88080384);            //  1 MB [B][SEG][D]

  cvt_f32_bf16<<<2048, 256, 0, stream>>>(x, xb, M_ * K_ / 4);
  cvt_f32_bf16<<<1024, 256, 0, stream>>>(Wd, wdb, D_ * K_ / 4);
  cvt_f32_bf16<<<16, 256, 0, stream>>>(Wb, wbb, N_ * K_ / 4);
  bx_mfma<<<dim3(M_ / 64), 256, 0, stream>>>(xb, wbb, bx);
  gemm_dt<<<dim3((M_ / 128) * (D_ / 128)), 256, 0, stream>>>(xb, wdb, bd, dtb);
  scan_p1<<<dim3(B_ * 4 * SEG_), 256, 0, stream>>>(dtb, bx, A, hseg, stot);
  scan_combine<<<dim3(B_ * (D_ / 16)), 256, 0, stream>>>(A, hseg, stot);
  scan_p3<<<dim3(B_ * 4 * SEG_), 256, 0, stream>>>(dtb, bx, xb, A, C, Dp, hseg, out);
}